// Round 13
// baseline (108.693 us; speedup 1.0000x reference)
//
#include <hip/hip_runtime.h>
#include <hip/hip_fp16.h>

// Problem constants (fixed by the reference setup)
constexpr int N = 4096;
constexpr int D = 512;
constexpr int NT = 32;                   // 4096 / 128 tile-rows
constexpr int NBLK = NT * (NT + 1) / 2;  // 528 upper-triangle tiles
constexpr float SENT = -1e30f;           // sentinel (invalid sites / empty slots)
constexpr unsigned TCV = 8386560u;       // N*(N-1)/2 valid strict-upper pairs

// Per-block candidate prefilter threshold. sims ~ N(0, 1/512); loss >= 0.60
// <=> s >= 0.10 (2.26 sigma) => ~194 candidates per full 128x128 block,
// ~97 per diagonal block. CCAP=320 is +9 sigma vs 194. Exactness NEVER
// depends on T0: blocks with cnt<10 or cnt>CCAP take the exact fallback.
constexpr float T0 = 0.60f;
constexpr unsigned CCAP = 320;

typedef _Float16 f16x8 __attribute__((ext_vector_type(8)));
typedef float f32x4 __attribute__((ext_vector_type(4)));

// async 16B/lane global->LDS (wave-uniform LDS base + lane*16)
__device__ __forceinline__ void load_lds16(const _Float16* g, _Float16* l) {
  __builtin_amdgcn_global_load_lds(
      (const __attribute__((address_space(1))) void*)g,
      (__attribute__((address_space(3))) void*)l, 16, 0, 0);
}

// Exact wave top-10 by repeated selection over per-lane register candidates.
// out[r] ends up wave-uniform. Duplicates preserved (leader pops ONE copy).
// NOTE: mutates vals[] on leader lanes.
template <int M>
__device__ __forceinline__ void wave_sel10(float (&vals)[M], float (&out)[10]) {
  int lane = threadIdx.x & 63;
  float lm = vals[0];
#pragma unroll
  for (int k = 1; k < M; k++) lm = fmaxf(lm, vals[k]);
#pragma unroll
  for (int r = 0; r < 10; r++) {
    float wmx = lm;
#pragma unroll
    for (int ofs = 1; ofs < 64; ofs <<= 1)
      wmx = fmaxf(wmx, __shfl_xor(wmx, ofs));
    out[r] = wmx;
    unsigned long long b = __ballot(lm == wmx);
    int leader = __ffsll(b) - 1;
    if (lane == leader) {
      bool found = false;
#pragma unroll
      for (int k = 0; k < M; k++) {
        bool hit = !found && (vals[k] == wmx);
        vals[k] = hit ? SENT : vals[k];
        found = found || hit;
      }
      lm = vals[0];
#pragma unroll
      for (int k = 1; k < M; k++) lm = fmaxf(lm, vals[k]);
    }
  }
}

// ws layout (float indices unless noted):
//   [0, 528)       f32 blk_sumv
//   [528, 1056)    f32 blk_sump
//   [1056, 1584)   u32 cntpack  (cntp | zeros<<16; per-block totals <= 16384)
//   [1584, 6864)   f32 top10g[528*10]
//   byte 32768:    f16 Xh[N*D]  (row-major)
constexpr int TOP10G_IDX = 1584;
constexpr int XH_OFF = 32768;

// ---------------- K0: fp32 -> f16 convert ----------------
__global__ void prep_kernel(const float4* __restrict__ X4,
                            ushort4* __restrict__ Xh4) {
  int gid = blockIdx.x * 256 + threadIdx.x;  // grid exactly N*D/4 threads
  float4 v = X4[gid];
  ushort4 o;
  o.x = __half_as_ushort(__float2half_rn(v.x));
  o.y = __half_as_ushort(__float2half_rn(v.y));
  o.z = __half_as_ushort(__float2half_rn(v.z));
  o.w = __half_as_ushort(__float2half_rn(v.w));
  Xh4[gid] = o;
}

// ---------------- K1: R12 champion + BK=64 (single-variable change) --------
// 528 blocks x 256 threads (4 waves, 2x2 wave grid, 64x64 per wave).
// R13 change: BK 32 -> 64. Rationale: the grid supplies only 528/256 = 2.06
// blocks/CU, so the BK=32 choice's "3 blocks/CU" headroom is unreachable —
// doubling LDS to 64KB (2 blocks/CU) is free on the occupancy axis and
// HALVES the count of per-step full vmcnt-drain barriers (16 -> 8), the one
// structurally-proven cost of this schedule (R7-R10: it cannot be pipelined
// away at source level, only amortized). Per step: 32 MFMA vs one drain.
// Swizzle reverts to R1's harness-verified 64-col pattern: LDS pos p of row
// r holds global chunk p^(r&7); read key lrow&7 (row bases are multiples of
// 16); 2-way bank aliasing = free (m136).
// Kept from R12: XCD work swizzle (bijective, 528=8*66), deadWave skip,
// LDS-atomic prefilter epilogue, exact fallback.
__global__ __launch_bounds__(256, 2) void gemm_stats_kernel(
    const _Float16* __restrict__ Xh, const int* __restrict__ tgt,
    float* __restrict__ slots, float* __restrict__ top10g) {
  __shared__ _Float16 As[2][128 * 64];  // 2 x 16 KB
  __shared__ _Float16 Bs[2][128 * 64];  // 2 x 16 KB
  __shared__ int tA[128], tB[128];
  __shared__ float redf[2][4];
  __shared__ unsigned redu[4];
  __shared__ float wml[40];  // fallback only
  __shared__ float cbuf[CCAP];
  __shared__ unsigned ccnt;

  int tid = threadIdx.x;
  if (tid == 0) ccnt = 0u;  // visible after first K-loop barrier

  // XCD-aware work swizzle, then decode upper-triangle tile (br <= bc)
  int id = (blockIdx.x & 7) * 66 + (blockIdx.x >> 3);
  int br = 0;
  while (id >= (NT - br)) { id -= (NT - br); br++; }
  int bc = br + id;

  if (tid < 128) tA[tid] = tgt[br * 128 + tid];
  else tB[tid - 128] = tgt[bc * 128 + (tid - 128)];

  int lane = tid & 63, wave = tid >> 6;
  int wm2 = (wave >> 1) << 6;  // 0 or 64: wave row-half
  int wn2 = (wave & 1) << 6;   // 0 or 64: wave col-half
  int lrow = lane & 15;
  int q4 = lane >> 4;          // k-chunk 0..3 (8 f16 each)
  int x7 = lrow & 7;           // 64-col swizzle key (R1-verified)
  int quad4 = q4 * 4;

  // diag blocks: wave 2 (rows 64..127 x cols 0..63) is entirely j < i
  bool deadWave = (br == bc) && (wave == 2);

  // staging: 1024 16B chunks per matrix per K-step (128 rows x 64 cols);
  // issue i (0..3) covers C = (i*4+wave)*64 + lane; row=C>>3, pos p=C&7
  // holds global chunk p^(row&7). LDS dest linear: base (i*4+wave)*512
  // elems + lane*8 (HW).
  int srow[4], scol[4], sdst[4];
#pragma unroll
  for (int i = 0; i < 4; i++) {
    int C = (i * 4 + wave) * 64 + lane;
    int row = C >> 3, p = C & 7;
    srow[i] = row;
    scol[i] = (p ^ (row & 7)) * 8;
    sdst[i] = (i * 4 + wave) * 512;  // wave-uniform elem base (+lane*8 by HW)
  }
  const _Float16* Arow = Xh + (size_t)(br * 128) * D;
  const _Float16* Brow = Xh + (size_t)(bc * 128) * D;

  // prologue: stage k0=0 into buffer 0
#pragma unroll
  for (int i = 0; i < 4; i++) {
    load_lds16(Arow + srow[i] * D + scol[i], &As[0][sdst[i]]);
    load_lds16(Brow + srow[i] * D + scol[i], &Bs[0][sdst[i]]);
  }

  f32x4 acc[4][4] = {};
#pragma unroll
  for (int t = 0; t < 8; t++) {
    int cur = t & 1;
    __syncthreads();  // drains vmcnt: buf[cur] visible; buf[cur^1] free
    if (t < 7) {
      int k0 = (t + 1) * 64;
#pragma unroll
      for (int i = 0; i < 4; i++) {
        load_lds16(Arow + srow[i] * D + k0 + scol[i], &As[cur ^ 1][sdst[i]]);
        load_lds16(Brow + srow[i] * D + k0 + scol[i], &Bs[cur ^ 1][sdst[i]]);
      }
    }
    if (!deadWave) {
#pragma unroll
      for (int ks = 0; ks < 64; ks += 32) {
        int c0 = ks >> 3;
        f16x8 af[4], bf[4];
#pragma unroll
        for (int mi = 0; mi < 4; mi++)
          af[mi] = *(const f16x8*)&As[cur][(wm2 + mi * 16 + lrow) * 64 +
                                           ((c0 + q4) ^ x7) * 8];
#pragma unroll
        for (int ni = 0; ni < 4; ni++)
          bf[ni] = *(const f16x8*)&Bs[cur][(wn2 + ni * 16 + lrow) * 64 +
                                           ((c0 + q4) ^ x7) * 8];
#pragma unroll
        for (int mi = 0; mi < 4; mi++)
#pragma unroll
          for (int ni = 0; ni < 4; ni++)
            acc[mi][ni] = __builtin_amdgcn_mfma_f32_16x16x32_f16(
                af[mi], bf[ni], acc[mi][ni], 0, 0, 0);
      }
    }
  }

  // ---- epilogue: stats + LDS-atomic candidate prefilter (loss inline) ----
  int tj[4];
#pragma unroll
  for (int ni = 0; ni < 4; ni++) tj[ni] = tB[wn2 + ni * 16 + lrow];

  float lsv = 0.f, lsp = 0.f;
  unsigned cz = 0;  // cntp | zeros<<16 (block totals <= 16384 each)
  int ib = br * 128 + wm2 + quad4;
  int jb = bc * 128 + wn2 + lrow;
#pragma unroll
  for (int mi = 0; mi < 4; mi++) {
#pragma unroll
    for (int r = 0; r < 4; r++) {
      int trow = tA[wm2 + mi * 16 + quad4 + r];
      int i = ib + mi * 16 + r;
#pragma unroll
      for (int ni = 0; ni < 4; ni++) {
        float s = acc[mi][ni][r];
        int j = jb + ni * 16;
        bool valid = j > i;  // strict upper triangle; doubled at the end
        bool pos = valid && (trow == tj[ni]);
        float loss = fmaxf(0.5f + (pos ? -s : s), 0.0f);
        if (valid) {
          lsv += s;
          if (loss == 0.0f) cz += 0x10000u;
          if (loss >= T0) {  // ~194/block: LDS atomic push
            unsigned p = atomicAdd(&ccnt, 1u);
            if (p < CCAP) cbuf[p] = loss;
          }
        }
        if (pos) { lsp += s; cz += 1u; }
      }
    }
  }
#pragma unroll
  for (int o = 32; o > 0; o >>= 1) {
    lsv += __shfl_down(lsv, o);
    lsp += __shfl_down(lsp, o);
    cz += __shfl_down(cz, o);
  }
  if (lane == 0) {
    redf[0][wave] = lsv; redf[1][wave] = lsp; redu[wave] = cz;
  }
  __syncthreads();  // ccnt final; redf/redu visible

  // stats store on wave 3 (overlaps wave 0's selection)
  if (tid == 192) {
    float a = 0.f, b = 0.f;
    unsigned c = 0;
#pragma unroll
    for (int w = 0; w < 4; w++) { a += redf[0][w]; b += redf[1][w]; c += redu[w]; }
    slots[blockIdx.x] = a;
    slots[NBLK + blockIdx.x] = b;
    ((unsigned*)slots)[2 * NBLK + blockIdx.x] = c;
  }

  unsigned cc = ccnt;  // block-uniform
  if (cc >= 10u && cc <= CCAP) {
    // fast path (always, statistically): block top-10 == top-10 of candidates
    if (wave == 0) {
      float m5[5];
#pragma unroll
      for (int k = 0; k < 5; k++) {
        unsigned g = lane + k * 64u;
        m5[k] = (g < cc) ? cbuf[g] : SENT;
      }
      float b10[10];
      wave_sel10<5>(m5, b10);
      if (lane == 0) {
#pragma unroll
        for (int r = 0; r < 10; r++) top10g[blockIdx.x * 10 + r] = b10[r];
      }
    }
  } else {
    // exact fallback (safety net; ~never taken at T0=0.60): rebuild losses,
    // per-wave selection over 64 regs (scratch OK here), 40 -> 10 merge
    float vals[64];
#pragma unroll
    for (int mi = 0; mi < 4; mi++) {
#pragma unroll
      for (int r = 0; r < 4; r++) {
        int trow = tA[wm2 + mi * 16 + quad4 + r];
        int i = ib + mi * 16 + r;
#pragma unroll
        for (int ni = 0; ni < 4; ni++) {
          float s = acc[mi][ni][r];
          int j = jb + ni * 16;
          bool valid = j > i;
          bool pos = valid && (trow == tj[ni]);
          float loss = fmaxf(0.5f + (pos ? -s : s), 0.0f);
          vals[(mi * 4 + ni) * 4 + r] = valid ? loss : SENT;
        }
      }
    }
    float wl[10];
    wave_sel10<64>(vals, wl);
    if (lane == 0) {
#pragma unroll
      for (int r = 0; r < 10; r++) wml[wave * 10 + r] = wl[r];
    }
    __syncthreads();
    if (wave == 0) {
      float m1[1];
      m1[0] = (lane < 40) ? wml[lane] : SENT;
      float b10[10];
      wave_sel10<1>(m1, b10);
      if (lane == 0) {
#pragma unroll
        for (int r = 0; r < 10; r++) top10g[blockIdx.x * 10 + r] = b10[r];
      }
    }
  }
}

// ---------------- K2: ONE-block finalize (1024 threads, 16 waves) ----------
// R6/R12's champion version: plain full merge (528 stat rows + 5280-float
// top-10). R8/R11 proved the "pruned" variant's extra serial stages cost
// +3us vs this simple wide merge — fewer sync stages wins at this scale.
__global__ __launch_bounds__(1024) void finalize_kernel(
    const float* __restrict__ slots, const float* __restrict__ top10g,
    float* __restrict__ out) {
  __shared__ float wml[160];
  __shared__ float redf[2][16];
  __shared__ unsigned redu[2][16];

  int tid = threadIdx.x, lane = tid & 63, wave = tid >> 6;

  // stats over 528 block rows (threads 0..527 each load one row)
  float sv = 0.f, sp = 0.f;
  unsigned cv = 0, zz = 0;
  if (tid < NBLK) {
    sv = slots[tid];
    sp = slots[NBLK + tid];
    unsigned c = ((const unsigned*)slots)[2 * NBLK + tid];
    cv = c & 0xffffu;
    zz = c >> 16;
  }

  // top-10 over 5280 floats: 16 waves x 6 regs (covers 6144 slots)
  float v6[6];
#pragma unroll
  for (int k = 0; k < 6; k++) {
    int g = tid + k * 1024;
    v6[k] = (g < NBLK * 10) ? top10g[g] : SENT;
  }

#pragma unroll
  for (int o = 32; o > 0; o >>= 1) {
    sv += __shfl_down(sv, o);
    sp += __shfl_down(sp, o);
    cv += __shfl_down(cv, o);
    zz += __shfl_down(zz, o);
  }
  if (lane == 0) {
    redf[0][wave] = sv; redf[1][wave] = sp;
    redu[0][wave] = cv; redu[1][wave] = zz;
  }

  float wl[10];
  wave_sel10<6>(v6, wl);
  if (lane == 0) {
#pragma unroll
    for (int r = 0; r < 10; r++) wml[wave * 10 + r] = wl[r];
  }
  __syncthreads();

  if (wave == 0) {
    float m3[3];
#pragma unroll
    for (int k = 0; k < 3; k++) {
      int g = lane + k * 64;
      m3[k] = (g < 160) ? wml[g] : SENT;
    }
    float f10[10];
    wave_sel10<3>(m3, f10);
    if (lane == 0) {
      float topsum = 0.f;
#pragma unroll
      for (int r = 0; r < 10; r++) topsum += f10[r];
      float tsv = 0.f, tsp = 0.f;
      unsigned tcv = 0, tzz = 0;
#pragma unroll
      for (int w = 0; w < 16; w++) {
        tsv += redf[0][w]; tsp += redf[1][w];
        tcv += redu[0][w]; tzz += redu[1][w];
      }
      // full-matrix multiset = upper-triangle doubled: top-20 mean == top-10
      // mean; counts double in numerator and denominator (cancel in means)
      out[0] = topsum * 0.1f;
      out[1] = (float)(2u * tzz);
      out[2] = tsp / (float)tcv;
      out[3] = (tsv - tsp) / (float)(TCV - tcv);
    }
  }
}

extern "C" void kernel_launch(void* const* d_in, const int* in_sizes, int n_in,
                              void* d_out, int out_size, void* d_ws,
                              size_t ws_size, hipStream_t stream) {
  const float* X = (const float*)d_in[0];
  const int* tgt = (const int*)d_in[1];
  float* out = (float*)d_out;
  char* ws = (char*)d_ws;

  float* slots = (float*)ws;
  float* top10g = slots + TOP10G_IDX;
  _Float16* Xh = (_Float16*)(ws + XH_OFF);

  prep_kernel<<<(N * D / 4) / 256, 256, 0, stream>>>((const float4*)X,
                                                     (ushort4*)Xh);
  gemm_stats_kernel<<<NBLK, 256, 0, stream>>>(Xh, tgt, slots, top10g);
  finalize_kernel<<<1, 1024, 0, stream>>>(slots, top10g, out);
}

// Round 14
// 96.396 us; speedup vs baseline: 1.1276x; 1.1276x over previous
//
#include <hip/hip_runtime.h>
#include <hip/hip_fp16.h>

// Problem constants (fixed by the reference setup)
constexpr int N = 4096;
constexpr int D = 512;
constexpr int NT = 32;                   // 4096 / 128 tile-rows
constexpr int NBLK = NT * (NT + 1) / 2;  // 528 upper-triangle tiles
constexpr float SENT = -1e30f;           // sentinel (invalid sites / empty slots)
constexpr unsigned TCV = 8386560u;       // N*(N-1)/2 valid strict-upper pairs

// Per-block candidate prefilter threshold. sims ~ N(0, 1/512); loss >= 0.60
// <=> s >= 0.10 (2.26 sigma) => ~194 candidates per full 128x128 block,
// ~97 per diagonal block. CCAP=320 is +9 sigma vs 194. Exactness NEVER
// depends on T0: blocks with cnt<10 or cnt>CCAP take the exact fallback.
constexpr float T0 = 0.60f;
constexpr unsigned CCAP = 320;

typedef _Float16 f16x8 __attribute__((ext_vector_type(8)));
typedef float f32x4 __attribute__((ext_vector_type(4)));

// async 16B/lane global->LDS (wave-uniform LDS base + lane*16)
__device__ __forceinline__ void load_lds16(const _Float16* g, _Float16* l) {
  __builtin_amdgcn_global_load_lds(
      (const __attribute__((address_space(1))) void*)g,
      (__attribute__((address_space(3))) void*)l, 16, 0, 0);
}

// Exact wave top-10 by repeated selection over per-lane register candidates.
// out[r] ends up wave-uniform. Duplicates preserved (leader pops ONE copy).
// NOTE: mutates vals[] on leader lanes.
template <int M>
__device__ __forceinline__ void wave_sel10(float (&vals)[M], float (&out)[10]) {
  int lane = threadIdx.x & 63;
  float lm = vals[0];
#pragma unroll
  for (int k = 1; k < M; k++) lm = fmaxf(lm, vals[k]);
#pragma unroll
  for (int r = 0; r < 10; r++) {
    float wmx = lm;
#pragma unroll
    for (int ofs = 1; ofs < 64; ofs <<= 1)
      wmx = fmaxf(wmx, __shfl_xor(wmx, ofs));
    out[r] = wmx;
    unsigned long long b = __ballot(lm == wmx);
    int leader = __ffsll(b) - 1;
    if (lane == leader) {
      bool found = false;
#pragma unroll
      for (int k = 0; k < M; k++) {
        bool hit = !found && (vals[k] == wmx);
        vals[k] = hit ? SENT : vals[k];
        found = found || hit;
      }
      lm = vals[0];
#pragma unroll
      for (int k = 1; k < M; k++) lm = fmaxf(lm, vals[k]);
    }
  }
}

// ws layout (float indices unless noted):
//   [0, 528)       f32 blk_sumv
//   [528, 1056)    f32 blk_sump
//   [1056, 1584)   u32 cntpack  (cntp | zeros<<16; per-block totals <= 16384)
//   [1584, 6864)   f32 top10g[528*10]
//   byte 32768:    f16 Xh[N*D]  (row-major)
constexpr int TOP10G_IDX = 1584;
constexpr int XH_OFF = 32768;

// ---------------- K0: fp32 -> f16 convert ----------------
__global__ void prep_kernel(const float4* __restrict__ X4,
                            ushort4* __restrict__ Xh4) {
  int gid = blockIdx.x * 256 + threadIdx.x;  // grid exactly N*D/4 threads
  float4 v = X4[gid];
  ushort4 o;
  o.x = __half_as_ushort(__float2half_rn(v.x));
  o.y = __half_as_ushort(__float2half_rn(v.y));
  o.z = __half_as_ushort(__float2half_rn(v.z));
  o.w = __half_as_ushort(__float2half_rn(v.w));
  Xh4[gid] = o;
}

// ---------------- K1: session champion (R12, 96.3us) -----------------------
// 528 blocks x 256 threads (4 waves, 2x2 wave grid, 64x64 per wave), BK=32,
// 2-buf LDS + one __syncthreads per K-step. R13's BK=64 test regressed
// (96.3 -> 108.7): at 2 blocks/CU the grid tail loses overlap and each
// drain waits on 2x staged bytes — BK=32 with 3 blocks/CU is the measured
// optimum for this simple 2-barrier schedule (consistent with learn_hip
// m132's BK=128 regression). Includes: XCD work swizzle (bijective,
// 528=8*66), deadWave skip on diag blocks, LDS-atomic prefilter epilogue
// with exact fallback.
// LDS swizzle (verified R6/R12): pos p of row r holds chunk p^((r>>1)&3);
// read key (lrow>>1)&3 is wave-invariant (row bases multiples of 16).
__global__ __launch_bounds__(256, 3) void gemm_stats_kernel(
    const _Float16* __restrict__ Xh, const int* __restrict__ tgt,
    float* __restrict__ slots, float* __restrict__ top10g) {
  __shared__ _Float16 As[2][128 * 32];  // 2 x 8 KB
  __shared__ _Float16 Bs[2][128 * 32];  // 2 x 8 KB
  __shared__ int tA[128], tB[128];
  __shared__ float redf[2][4];
  __shared__ unsigned redu[4];
  __shared__ float wml[40];  // fallback only
  __shared__ float cbuf[CCAP];
  __shared__ unsigned ccnt;

  int tid = threadIdx.x;
  if (tid == 0) ccnt = 0u;  // visible after first K-loop barrier

  // XCD-aware work swizzle, then decode upper-triangle tile (br <= bc)
  int id = (blockIdx.x & 7) * 66 + (blockIdx.x >> 3);
  int br = 0;
  while (id >= (NT - br)) { id -= (NT - br); br++; }
  int bc = br + id;

  if (tid < 128) tA[tid] = tgt[br * 128 + tid];
  else tB[tid - 128] = tgt[bc * 128 + (tid - 128)];

  int lane = tid & 63, wave = tid >> 6;
  int wm2 = (wave >> 1) << 6;  // 0 or 64: wave row-half
  int wn2 = (wave & 1) << 6;   // 0 or 64: wave col-half
  int lrow = lane & 15;
  int q4 = lane >> 4;          // k-chunk 0..3 (8 f16 each)
  int xk = (lrow >> 1) & 3;    // 32-col swizzle key
  int quad4 = q4 * 4;

  // diag blocks: wave 2 (rows 64..127 x cols 0..63) is entirely j < i
  bool deadWave = (br == bc) && (wave == 2);

  // staging: 512 16B chunks per matrix per K-step; issue i covers
  // C = i*256 + tid; row=C>>2, pos p=C&3 holds global chunk p^((row>>1)&3)
  int srow[2], scol[2], sdst[2];
#pragma unroll
  for (int i = 0; i < 2; i++) {
    int C = i * 256 + tid;
    int row = C >> 2, p = C & 3;
    srow[i] = row;
    scol[i] = (p ^ ((row >> 1) & 3)) * 8;
    sdst[i] = (i * 4 + wave) * 512;  // wave-uniform elem base (+lane*8 by HW)
  }
  const _Float16* Arow = Xh + (size_t)(br * 128) * D;
  const _Float16* Brow = Xh + (size_t)(bc * 128) * D;

  // prologue: stage k0=0 into buffer 0
#pragma unroll
  for (int i = 0; i < 2; i++) {
    load_lds16(Arow + srow[i] * D + scol[i], &As[0][sdst[i]]);
    load_lds16(Brow + srow[i] * D + scol[i], &Bs[0][sdst[i]]);
  }

  f32x4 acc[4][4] = {};
#pragma unroll
  for (int t = 0; t < 16; t++) {
    int cur = t & 1;
    __syncthreads();  // drains vmcnt: buf[cur] visible; buf[cur^1] free
    if (t < 15) {
      int k0 = (t + 1) * 32;
#pragma unroll
      for (int i = 0; i < 2; i++) {
        load_lds16(Arow + srow[i] * D + k0 + scol[i], &As[cur ^ 1][sdst[i]]);
        load_lds16(Brow + srow[i] * D + k0 + scol[i], &Bs[cur ^ 1][sdst[i]]);
      }
    }
    if (!deadWave) {
      f16x8 af[4], bf[4];
#pragma unroll
      for (int mi = 0; mi < 4; mi++)
        af[mi] = *(const f16x8*)&As[cur][(wm2 + mi * 16 + lrow) * 32 +
                                         (q4 ^ xk) * 8];
#pragma unroll
      for (int ni = 0; ni < 4; ni++)
        bf[ni] = *(const f16x8*)&Bs[cur][(wn2 + ni * 16 + lrow) * 32 +
                                         (q4 ^ xk) * 8];
#pragma unroll
      for (int mi = 0; mi < 4; mi++)
#pragma unroll
        for (int ni = 0; ni < 4; ni++)
          acc[mi][ni] = __builtin_amdgcn_mfma_f32_16x16x32_f16(
              af[mi], bf[ni], acc[mi][ni], 0, 0, 0);
    }
  }

  // ---- epilogue: stats + LDS-atomic candidate prefilter (loss inline) ----
  int tj[4];
#pragma unroll
  for (int ni = 0; ni < 4; ni++) tj[ni] = tB[wn2 + ni * 16 + lrow];

  float lsv = 0.f, lsp = 0.f;
  unsigned cz = 0;  // cntp | zeros<<16 (block totals <= 16384 each)
  int ib = br * 128 + wm2 + quad4;
  int jb = bc * 128 + wn2 + lrow;
#pragma unroll
  for (int mi = 0; mi < 4; mi++) {
#pragma unroll
    for (int r = 0; r < 4; r++) {
      int trow = tA[wm2 + mi * 16 + quad4 + r];
      int i = ib + mi * 16 + r;
#pragma unroll
      for (int ni = 0; ni < 4; ni++) {
        float s = acc[mi][ni][r];
        int j = jb + ni * 16;
        bool valid = j > i;  // strict upper triangle; doubled at the end
        bool pos = valid && (trow == tj[ni]);
        float loss = fmaxf(0.5f + (pos ? -s : s), 0.0f);
        if (valid) {
          lsv += s;
          if (loss == 0.0f) cz += 0x10000u;
          if (loss >= T0) {  // ~194/block: LDS atomic push
            unsigned p = atomicAdd(&ccnt, 1u);
            if (p < CCAP) cbuf[p] = loss;
          }
        }
        if (pos) { lsp += s; cz += 1u; }
      }
    }
  }
#pragma unroll
  for (int o = 32; o > 0; o >>= 1) {
    lsv += __shfl_down(lsv, o);
    lsp += __shfl_down(lsp, o);
    cz += __shfl_down(cz, o);
  }
  if (lane == 0) {
    redf[0][wave] = lsv; redf[1][wave] = lsp; redu[wave] = cz;
  }
  __syncthreads();  // ccnt final; redf/redu visible

  // stats store on wave 3 (overlaps wave 0's selection)
  if (tid == 192) {
    float a = 0.f, b = 0.f;
    unsigned c = 0;
#pragma unroll
    for (int w = 0; w < 4; w++) { a += redf[0][w]; b += redf[1][w]; c += redu[w]; }
    slots[blockIdx.x] = a;
    slots[NBLK + blockIdx.x] = b;
    ((unsigned*)slots)[2 * NBLK + blockIdx.x] = c;
  }

  unsigned cc = ccnt;  // block-uniform
  if (cc >= 10u && cc <= CCAP) {
    // fast path (always, statistically): block top-10 == top-10 of candidates
    if (wave == 0) {
      float m5[5];
#pragma unroll
      for (int k = 0; k < 5; k++) {
        unsigned g = lane + k * 64u;
        m5[k] = (g < cc) ? cbuf[g] : SENT;
      }
      float b10[10];
      wave_sel10<5>(m5, b10);
      if (lane == 0) {
#pragma unroll
        for (int r = 0; r < 10; r++) top10g[blockIdx.x * 10 + r] = b10[r];
      }
    }
  } else {
    // exact fallback (safety net; ~never taken at T0=0.60): rebuild losses,
    // per-wave selection over 64 regs (scratch OK here), 40 -> 10 merge
    float vals[64];
#pragma unroll
    for (int mi = 0; mi < 4; mi++) {
#pragma unroll
      for (int r = 0; r < 4; r++) {
        int trow = tA[wm2 + mi * 16 + quad4 + r];
        int i = ib + mi * 16 + r;
#pragma unroll
        for (int ni = 0; ni < 4; ni++) {
          float s = acc[mi][ni][r];
          int j = jb + ni * 16;
          bool valid = j > i;
          bool pos = valid && (trow == tj[ni]);
          float loss = fmaxf(0.5f + (pos ? -s : s), 0.0f);
          vals[(mi * 4 + ni) * 4 + r] = valid ? loss : SENT;
        }
      }
    }
    float wl[10];
    wave_sel10<64>(vals, wl);
    if (lane == 0) {
#pragma unroll
      for (int r = 0; r < 10; r++) wml[wave * 10 + r] = wl[r];
    }
    __syncthreads();
    if (wave == 0) {
      float m1[1];
      m1[0] = (lane < 40) ? wml[lane] : SENT;
      float b10[10];
      wave_sel10<1>(m1, b10);
      if (lane == 0) {
#pragma unroll
        for (int r = 0; r < 10; r++) top10g[blockIdx.x * 10 + r] = b10[r];
      }
    }
  }
}

// ---------------- K2: ONE-block finalize (1024 threads, 16 waves) ----------
// Champion version: plain full merge (528 stat rows + 5280-float top-10).
// R8/R11 proved the "pruned" variant's extra serial stages cost +3us vs
// this simple wide merge — fewer sync stages wins at this scale.
__global__ __launch_bounds__(1024) void finalize_kernel(
    const float* __restrict__ slots, const float* __restrict__ top10g,
    float* __restrict__ out) {
  __shared__ float wml[160];
  __shared__ float redf[2][16];
  __shared__ unsigned redu[2][16];

  int tid = threadIdx.x, lane = tid & 63, wave = tid >> 6;

  // stats over 528 block rows (threads 0..527 each load one row)
  float sv = 0.f, sp = 0.f;
  unsigned cv = 0, zz = 0;
  if (tid < NBLK) {
    sv = slots[tid];
    sp = slots[NBLK + tid];
    unsigned c = ((const unsigned*)slots)[2 * NBLK + tid];
    cv = c & 0xffffu;
    zz = c >> 16;
  }

  // top-10 over 5280 floats: 16 waves x 6 regs (covers 6144 slots)
  float v6[6];
#pragma unroll
  for (int k = 0; k < 6; k++) {
    int g = tid + k * 1024;
    v6[k] = (g < NBLK * 10) ? top10g[g] : SENT;
  }

#pragma unroll
  for (int o = 32; o > 0; o >>= 1) {
    sv += __shfl_down(sv, o);
    sp += __shfl_down(sp, o);
    cv += __shfl_down(cv, o);
    zz += __shfl_down(zz, o);
  }
  if (lane == 0) {
    redf[0][wave] = sv; redf[1][wave] = sp;
    redu[0][wave] = cv; redu[1][wave] = zz;
  }

  float wl[10];
  wave_sel10<6>(v6, wl);
  if (lane == 0) {
#pragma unroll
    for (int r = 0; r < 10; r++) wml[wave * 10 + r] = wl[r];
  }
  __syncthreads();

  if (wave == 0) {
    float m3[3];
#pragma unroll
    for (int k = 0; k < 3; k++) {
      int g = lane + k * 64;
      m3[k] = (g < 160) ? wml[g] : SENT;
    }
    float f10[10];
    wave_sel10<3>(m3, f10);
    if (lane == 0) {
      float topsum = 0.f;
#pragma unroll
      for (int r = 0; r < 10; r++) topsum += f10[r];
      float tsv = 0.f, tsp = 0.f;
      unsigned tcv = 0, tzz = 0;
#pragma unroll
      for (int w = 0; w < 16; w++) {
        tsv += redf[0][w]; tsp += redf[1][w];
        tcv += redu[0][w]; tzz += redu[1][w];
      }
      // full-matrix multiset = upper-triangle doubled: top-20 mean == top-10
      // mean; counts double in numerator and denominator (cancel in means)
      out[0] = topsum * 0.1f;
      out[1] = (float)(2u * tzz);
      out[2] = tsp / (float)tcv;
      out[3] = (tsv - tsp) / (float)(TCV - tcv);
    }
  }
}

extern "C" void kernel_launch(void* const* d_in, const int* in_sizes, int n_in,
                              void* d_out, int out_size, void* d_ws,
                              size_t ws_size, hipStream_t stream) {
  const float* X = (const float*)d_in[0];
  const int* tgt = (const int*)d_in[1];
  float* out = (float*)d_out;
  char* ws = (char*)d_ws;

  float* slots = (float*)ws;
  float* top10g = slots + TOP10G_IDX;
  _Float16* Xh = (_Float16*)(ws + XH_OFF);

  prep_kernel<<<(N * D / 4) / 256, 256, 0, stream>>>((const float4*)X,
                                                     (ushort4*)Xh);
  gemm_stats_kernel<<<NBLK, 256, 0, stream>>>(Xh, tgt, slots, top10g);
  finalize_kernel<<<1, 1024, 0, stream>>>(slots, top10g, out);
}